// Round 10
// baseline (256.016 us; speedup 1.0000x reference)
//
#include <hip/hip_runtime.h>

// TGCNCell forward:
//   h_agg = segment_sum(x[src], dst);  gates = h_agg @ W_ih.T + b_ih + b_hh
//   c = sigm(i)*tanh(g); h = sigm(o)*tanh(c); out = relu(h)
// f-gate rows (32:64) and W_hh are numerically unused.
//
// R10: two kernels only. pA sorts edges into 50 superbins (int4 loads,
// rank-trick LDS hist, wave-parallel scan, staged coalesced writeout).
// p2 (one block per 50-node bin, XCD-swizzled so the 40 sibling bins of a
// superbin share one XCD's L2) filters its edges straight out of the
// superbin segment, sorts by node in LDS, register-accumulates with 16-deep
// batched x loads, and fuses gates+activations. pB is gone; seg2 is gone.

constexpr int NN   = 100000;
constexpr int NE   = 1600000;
constexpr int F    = 32;
constexpr int NSB  = 50;            // superbins
constexpr int NPSB = 2000;          // nodes per superbin (dl2 fits 11 bits)
constexpr int CAP1 = 34816;         // Poisson(32000)+15.7sigma
constexpr int EPA  = 1600;          // edges per pA block
constexpr int NBA  = NE / EPA;      // 1000 blocks
constexpr int NPB  = 50;            // nodes per bin
constexpr int NBIN = NN / NPB;      // 2000 (divisible by 8 -> bijective swizzle)
constexpr int BPSB = NPSB / NPB;    // 40 bins per superbin
constexpr int CAP2 = 1024;          // per-bin edge cap, Poisson(800)+7.9sigma
static_assert(NSB * NPSB == NN, "superbin geometry");
static_assert(NBIN * NPB == NN, "bin geometry");
static_assert(NBA * EPA == NE, "edge partition");
static_assert(EPA % 4 == 0 && (EPA / 4) <= 512, "int4 load geometry");
static_assert(NBIN % 8 == 0, "bijective XCD swizzle");

// ---------------------------------------------------------------------------
// pA: bin edges by superbin. int4 edge loads; LDS rank-trick histogram;
// wave-parallel exclusive scan; staged scatter; coalesced run writeout
// (avg run = 1600/50 = 32 edges = 128B).
// ---------------------------------------------------------------------------
__global__ __launch_bounds__(256) void pA(
    const int* __restrict__ src, const int* __restrict__ dst,
    unsigned int* __restrict__ seg1, int* __restrict__ fill1)
{
    __shared__ int hist[NSB], sbase[NSB], gbase[NSB];
    __shared__ unsigned int stg[EPA];   // 6.4KB
    __shared__ unsigned char bid[EPA];  // 1.6KB

    const int t  = threadIdx.x;
    const int e0 = blockIdx.x * EPA;

    if (t < NSB) hist[t] = 0;
    __syncthreads();

    const int4* s4p = reinterpret_cast<const int4*>(src + e0);
    const int4* d4p = reinterpret_cast<const int4*>(dst + e0);
    int4 s4[2], d4[2];
    int  rR[8];

    #pragma unroll
    for (int j = 0; j < 2; ++j) {
        int idx = t + j * 256;
        if (idx < EPA / 4) { s4[j] = s4p[idx]; d4[j] = d4p[idx]; }
    }
    #pragma unroll
    for (int j = 0; j < 2; ++j) {
        int idx = t + j * 256;
        if (idx < EPA / 4) {
            const int* dd = &d4[j].x;
            #pragma unroll
            for (int k = 0; k < 4; ++k)
                rR[j * 4 + k] = atomicAdd(&hist[(unsigned)dd[k] / NPSB], 1);
        }
    }
    __syncthreads();

    // wave 0: exclusive scan of hist[0..49]
    if (t < 64) {
        int v = (t < NSB) ? hist[t] : 0;
        int incl = v;
        #pragma unroll
        for (int off = 1; off < 64; off <<= 1) {
            int u = __shfl_up(incl, off, 64);
            if (t >= off) incl += u;
        }
        if (t < NSB) sbase[t] = incl - v;
    }
    __syncthreads();

    if (t < NSB) { int c = hist[t]; gbase[t] = c ? atomicAdd(&fill1[t], c) : 0; }
    __syncthreads();

    #pragma unroll
    for (int j = 0; j < 2; ++j) {
        int idx = t + j * 256;
        if (idx < EPA / 4) {
            const int* dd = &d4[j].x;
            const int* ss = &s4[j].x;
            #pragma unroll
            for (int k = 0; k < 4; ++k) {
                unsigned d  = (unsigned)dd[k];
                unsigned sb = d / NPSB, dl2 = d - sb * NPSB;
                int lp  = sbase[sb] + rR[j * 4 + k];
                stg[lp] = ((unsigned)ss[k] << 11) | dl2;
                bid[lp] = (unsigned char)sb;
            }
        }
    }
    __syncthreads();

    for (int p = t; p < EPA; p += 256) {
        int b    = bid[p];
        int slot = gbase[b] + (p - sbase[b]);
        if (slot < CAP1) seg1[(size_t)b * CAP1 + slot] = stg[p];
    }
}

// ---------------------------------------------------------------------------
// p2: one block per bin. Filter the superbin segment (2 streamed passes:
// count, then rank+scatter src into node-sorted sgl), register-accumulate
// per group-owned node with 16-deep batched x loads, fused gates.
// ---------------------------------------------------------------------------
__device__ __forceinline__ float sigm(float v)  { return 1.0f / (1.0f + __expf(-v)); }
__device__ __forceinline__ float tanh_(float v) { return 1.0f - 2.0f / (__expf(2.0f * v) + 1.0f); }

__global__ __launch_bounds__(256) void p2(
    const float* __restrict__ x,
    const unsigned int* __restrict__ seg1, const int* __restrict__ fill1,
    const float* __restrict__ W,        // (128,32) row-major
    const float* __restrict__ b_ih, const float* __restrict__ b_hh,
    float* __restrict__ out)
{
    __shared__ float hs[NPB * F];       // 6.4KB
    __shared__ float Ws[96 * 33];       // 12.7KB, stride 33 conflict-free
    __shared__ float bs[96];
    __shared__ unsigned int sgl[CAP2];  // 4KB: node-sorted src list
    __shared__ int hist[NPB], start_[NPB], cur[NPB];

    const int t    = threadIdx.x;
    const int bid0 = blockIdx.x;
    const int bin  = (bid0 & 7) * (NBIN / 8) + (bid0 >> 3);  // XCD-chunked
    const int sb   = bin / BPSB;
    const int lo   = (bin % BPSB) * NPB;    // dl2 range [lo, lo+NPB)

    for (int i = t; i < 96 * 32; i += 256) {
        int r = i >> 5, k = i & 31;
        int sr = (r < 32) ? r : r + 32;     // skip f rows 32..63
        Ws[r * 33 + k] = W[sr * 32 + k];
    }
    if (t < 96) { int sr = (t < 32) ? t : t + 32; bs[t] = b_ih[sr] + b_hh[sr]; }
    if (t < NPB) hist[t] = 0;
    __syncthreads();

    int n1 = fill1[sb]; if (n1 > CAP1) n1 = CAP1;
    const unsigned int* s1 = seg1 + (size_t)sb * CAP1;

    // pass 1: count my nodes' edges (sentinel dl2=2047 never matches)
    for (int i0 = 0; i0 < n1; i0 += 1024) {
        unsigned v[4];
        #pragma unroll
        for (int k = 0; k < 4; ++k) {
            int i = i0 + k * 256 + t;
            v[k] = (i < n1) ? s1[i] : 0xFFFFFFFFu;
        }
        #pragma unroll
        for (int k = 0; k < 4; ++k) {
            int dl2 = (int)(v[k] & 2047u);
            if (dl2 >= lo && dl2 < lo + NPB) atomicAdd(&hist[dl2 - lo], 1);
        }
    }
    __syncthreads();

    // wave 0: exclusive scan of hist[0..49]
    if (t < 64) {
        int vv = (t < NPB) ? hist[t] : 0;
        int incl = vv;
        #pragma unroll
        for (int off = 1; off < 64; off <<= 1) {
            int u = __shfl_up(incl, off, 64);
            if (t >= off) incl += u;
        }
        if (t < NPB) start_[t] = incl - vv;
    }
    __syncthreads();
    if (t < NPB) cur[t] = start_[t];
    __syncthreads();

    // pass 2: rank + scatter src into node-sorted sgl
    for (int i0 = 0; i0 < n1; i0 += 1024) {
        unsigned v[4];
        #pragma unroll
        for (int k = 0; k < 4; ++k) {
            int i = i0 + k * 256 + t;
            v[k] = (i < n1) ? s1[i] : 0xFFFFFFFFu;
        }
        #pragma unroll
        for (int k = 0; k < 4; ++k) {
            int dl2 = (int)(v[k] & 2047u);
            if (dl2 >= lo && dl2 < lo + NPB) {
                int r = atomicAdd(&cur[dl2 - lo], 1);
                if (r < CAP2) sgl[r] = v[k] >> 11;      // src node id
            }
        }
    }
    __syncthreads();

    // gather: group g owns nodes dl = g + 8*m; register accumulate,
    // 16 independent x-row loads in flight per group
    const int lane = t & 31, g = t >> 5;
    for (int dl = g; dl < NPB; dl += 8) {
        int st = start_[dl], cn = hist[dl];
        if (st >= CAP2) cn = 0; else if (st + cn > CAP2) cn = CAP2 - st;
        float acc = 0.0f;
        for (int b = 0; b < cn; b += 16) {
            float xv[16];
            #pragma unroll
            for (int k = 0; k < 16; ++k) {
                int idx = b + k; if (idx > cn - 1) idx = cn - 1;  // clamp (dups masked)
                unsigned s = sgl[st + idx];     // broadcast LDS read
                xv[k] = x[s * F + lane];
            }
            #pragma unroll
            for (int k = 0; k < 16; ++k) acc += (b + k < cn) ? xv[k] : 0.0f;
        }
        hs[dl * F + lane] = acc;                // plain ds_write, once per node
    }
    __syncthreads();

    // gates: thread -> (node, col j)
    for (int i = t; i < NPB * F; i += 256) {
        int node = i >> 5, j = i & 31;
        const float* h  = &hs[node * F];
        const float* wi = &Ws[j * 33];
        const float* wg = &Ws[(32 + j) * 33];
        const float* wo = &Ws[(64 + j) * 33];
        float ai = bs[j], ag = bs[32 + j], ao = bs[64 + j];
        #pragma unroll
        for (int k = 0; k < F; ++k) {
            float hv = h[k];
            ai += hv * wi[k];
            ag += hv * wg[k];
            ao += hv * wo[k];
        }
        float c  = sigm(ai) * tanh_(ag);
        float hh = sigm(ao) * tanh_(c);
        out[(bin * NPB + node) * F + j] = fmaxf(hh, 0.0f);
    }
}

// ---------------------------------------------------------------------------
extern "C" void kernel_launch(void* const* d_in, const int* in_sizes, int n_in,
                              void* d_out, int out_size, void* d_ws, size_t ws_size,
                              hipStream_t stream) {
    const float* x    = (const float*)d_in[0];
    const int*   src  = (const int*)  d_in[1];
    const int*   dst  = (const int*)  d_in[2];
    const float* W_ih = (const float*)d_in[3];
    // d_in[4] = W_hh : numerically unused
    const float* b_ih = (const float*)d_in[5];
    const float* b_hh = (const float*)d_in[6];
    float* out = (float*)d_out;

    // ws layout: seg1 (50*34816*4 = 6.96MB) | fill1 (50 ints)
    unsigned int* seg1 = (unsigned int*)d_ws;
    int* fill1 = (int*)(seg1 + (size_t)NSB * CAP1);

    hipMemsetAsync(fill1, 0, NSB * sizeof(int), stream);
    pA<<<NBA,  256, 0, stream>>>(src, dst, seg1, fill1);
    p2<<<NBIN, 256, 0, stream>>>(x, seg1, fill1, W_ih, b_ih, b_hh, out);
}

// Round 12
// 147.589 us; speedup vs baseline: 1.7346x; 1.7346x over previous
//
#include <hip/hip_runtime.h>

// TGCNCell forward:
//   h_agg = segment_sum(x[src], dst);  gates = h_agg @ W_ih.T + b_ih + b_hh
//   c = sigm(i)*tanh(g); h = sigm(o)*tanh(c); out = relu(h)
// f-gate rows (32:64) and W_hh are numerically unused.
//
// R11 resubmit (bench never ran): R9 structure (pA superbin sort -> pB
// refine -> p2 gather+gates; p2 at its gather MSHR wall ~57us). Experiment:
// 8x-replicated fill1/seg1 so pA's reservation atomics spread over 8x more
// addresses (R8/R9 insensitivity suggests the 50-word returning-atomic
// queue is the pA critical path).

constexpr int NN   = 100000;
constexpr int NE   = 1600000;
constexpr int F    = 32;
// level 1: superbins, 8-way replicated segments
constexpr int NSB  = 50;            // superbins
constexpr int NPSB = 2000;          // nodes per superbin (dl2 fits 11 bits)
constexpr int NREP = 8;             // fill1/seg1 replicas (blockIdx & 7)
constexpr int CAP1R = 4352;         // per-(rep,sb) cap: mean 4000 + 5.6 sigma
constexpr int EPA  = 1600;          // edges per pA block
constexpr int NBA  = NE / EPA;      // 1000 blocks
// level 2: bins
constexpr int NPB  = 50;            // nodes per bin
constexpr int NBIN = NN / NPB;      // 2000 (divisible by 8 -> bijective swizzle)
constexpr int BPSB = NPSB / NPB;    // 40 bins per superbin
constexpr int CH2  = 2048;          // pB chunk
constexpr int CHPS = (CAP1R + CH2 - 1) / CH2;  // 3 chunks per sub-segment
constexpr int CAP2 = 1024;          // per-bin cap: mean 800 + 7.9 sigma
static_assert(NSB * NPSB == NN, "superbin geometry");
static_assert(NBIN * NPB == NN, "bin geometry");
static_assert(NBA * EPA == NE, "edge partition");
static_assert(NBIN % 8 == 0, "bijective XCD swizzle");
static_assert(CAP1R % 4 == 0, "int4 alignment");

// ---------------------------------------------------------------------------
// pA: bin edges by superbin into replica (blockIdx&7). int4 loads, LDS
// rank-trick histogram, wave-parallel scan, staged coalesced writeout.
// ---------------------------------------------------------------------------
__global__ __launch_bounds__(256) void pA(
    const int* __restrict__ src, const int* __restrict__ dst,
    unsigned int* __restrict__ seg1, int* __restrict__ fill1)
{
    __shared__ int hist[NSB], sbase[NSB], gbase[NSB];
    __shared__ unsigned int stg[EPA];   // 6.4KB
    __shared__ unsigned char bid[EPA];  // 1.6KB

    const int t  = threadIdx.x;
    const int e0 = blockIdx.x * EPA;
    const int g  = blockIdx.x & (NREP - 1);

    if (t < NSB) hist[t] = 0;
    __syncthreads();

    const int4* s4p = reinterpret_cast<const int4*>(src + e0);
    const int4* d4p = reinterpret_cast<const int4*>(dst + e0);
    int4 s4[2], d4[2];
    int  rR[8];

    #pragma unroll
    for (int j = 0; j < 2; ++j) {
        int idx = t + j * 256;
        if (idx < EPA / 4) { s4[j] = s4p[idx]; d4[j] = d4p[idx]; }
    }
    #pragma unroll
    for (int j = 0; j < 2; ++j) {
        int idx = t + j * 256;
        if (idx < EPA / 4) {
            const int* dd = &d4[j].x;
            #pragma unroll
            for (int k = 0; k < 4; ++k)
                rR[j * 4 + k] = atomicAdd(&hist[(unsigned)dd[k] / NPSB], 1);
        }
    }
    __syncthreads();

    // wave 0: exclusive scan of hist[0..49]
    if (t < 64) {
        int v = (t < NSB) ? hist[t] : 0;
        int incl = v;
        #pragma unroll
        for (int off = 1; off < 64; off <<= 1) {
            int u = __shfl_up(incl, off, 64);
            if (t >= off) incl += u;
        }
        if (t < NSB) sbase[t] = incl - v;
    }
    __syncthreads();

    if (t < NSB) {                       // reservation in replica g (contention/8)
        int c = hist[t];
        gbase[t] = c ? atomicAdd(&fill1[g * 64 + t], c) : 0;
    }
    __syncthreads();

    #pragma unroll
    for (int j = 0; j < 2; ++j) {
        int idx = t + j * 256;
        if (idx < EPA / 4) {
            const int* dd = &d4[j].x;
            const int* ss = &s4[j].x;
            #pragma unroll
            for (int k = 0; k < 4; ++k) {
                unsigned d  = (unsigned)dd[k];
                unsigned sb = d / NPSB, dl2 = d - sb * NPSB;
                int lp  = sbase[sb] + rR[j * 4 + k];
                stg[lp] = ((unsigned)ss[k] << 11) | dl2;
                bid[lp] = (unsigned char)sb;
            }
        }
    }
    __syncthreads();

    for (int p = t; p < EPA; p += 256) {
        int b    = bid[p];
        int slot = gbase[b] + (p - sbase[b]);
        if (slot < CAP1R) seg1[(size_t)(g * NSB + b) * CAP1R + slot] = stg[p];
    }
}

// ---------------------------------------------------------------------------
// pB: refine one 2048-edge chunk of one (replica, superbin) sub-segment into
// its 40 bins (rank trick, u8 bin-id writeout, int4 reads).
// ---------------------------------------------------------------------------
__global__ __launch_bounds__(256) void pB(
    const unsigned int* __restrict__ seg1, const int* __restrict__ fill1,
    unsigned int* __restrict__ seg2, int* __restrict__ fill2)
{
    __shared__ int hist[BPSB], sbase[BPSB], gbase[BPSB];
    __shared__ unsigned int stg[CH2];   // 8KB
    __shared__ unsigned char bid[CH2];  // 2KB

    const int t   = threadIdx.x;
    const int sb  = blockIdx.x / (NREP * CHPS);
    const int rem = blockIdx.x % (NREP * CHPS);
    const int g   = rem / CHPS;
    const int ch  = rem % CHPS;

    int n1 = fill1[g * 64 + sb]; if (n1 > CAP1R) n1 = CAP1R;
    int cnt = n1 - ch * CH2;
    if (cnt <= 0) return;               // uniform across block (before barriers)
    if (cnt > CH2) cnt = CH2;
    const unsigned int* sg = seg1 + (size_t)(g * NSB + sb) * CAP1R + ch * CH2;
    const int4* sg4 = reinterpret_cast<const int4*>(sg);

    if (t < BPSB) hist[t] = 0;
    __syncthreads();

    unsigned rV[8]; int rR[8];          // CH2/256 = 8 edges/thread
    #pragma unroll
    for (int j = 0; j < 2; ++j) {
        int idx = t + j * 256;
        if (4 * idx < cnt) {
            int4 v4 = sg4[idx];
            const unsigned* vv = reinterpret_cast<const unsigned*>(&v4.x);
            #pragma unroll
            for (int k = 0; k < 4; ++k) {
                int i = 4 * idx + k;
                unsigned v = vv[k];
                rV[j * 4 + k] = v;
                rR[j * 4 + k] = (i < cnt) ? atomicAdd(&hist[(v & 2047u) / NPB], 1) : 0;
            }
        } else {
            #pragma unroll
            for (int k = 0; k < 4; ++k) { rV[j * 4 + k] = 0; rR[j * 4 + k] = -1; }
        }
    }
    __syncthreads();

    // wave 0: exclusive scan of hist[0..39]
    if (t < 64) {
        int v = (t < BPSB) ? hist[t] : 0;
        int incl = v;
        #pragma unroll
        for (int off = 1; off < 64; off <<= 1) {
            int u = __shfl_up(incl, off, 64);
            if (t >= off) incl += u;
        }
        if (t < BPSB) sbase[t] = incl - v;
    }
    __syncthreads();

    if (t < BPSB) { int c = hist[t]; gbase[t] = c ? atomicAdd(&fill2[sb * BPSB + t], c) : 0; }
    __syncthreads();

    #pragma unroll
    for (int j = 0; j < 2; ++j) {
        int idx = t + j * 256;
        #pragma unroll
        for (int k = 0; k < 4; ++k) {
            int q = j * 4 + k;
            int i = 4 * idx + k;
            if (rR[q] >= 0 && i < cnt) {
                unsigned v = rV[q];
                unsigned s = v >> 11, dl2 = v & 2047u;
                unsigned lb = dl2 / NPB, dl = dl2 - lb * NPB;
                int lp  = sbase[lb] + rR[q];
                stg[lp] = (s << 8) | dl;
                bid[lp] = (unsigned char)lb;
            }
        }
    }
    __syncthreads();

    for (int p = t; p < cnt; p += 256) {
        int b    = bid[p];
        int slot = gbase[b] + (p - sbase[b]);
        if (slot < CAP2) seg2[(size_t)(sb * BPSB + b) * CAP2 + slot] = stg[p];
    }
}

// ---------------------------------------------------------------------------
// p2 (identical to R9's 57us version): one block per 50-node bin, in-LDS
// counting sort by node, register accumulation with 16-deep batched x loads,
// fused gates + activations.
// ---------------------------------------------------------------------------
__device__ __forceinline__ float sigm(float v)  { return 1.0f / (1.0f + __expf(-v)); }
__device__ __forceinline__ float tanh_(float v) { return 1.0f - 2.0f / (__expf(2.0f * v) + 1.0f); }

__global__ __launch_bounds__(256) void p2(
    const float* __restrict__ x,
    const unsigned int* __restrict__ seg2, const int* __restrict__ fill2,
    const float* __restrict__ W,        // (128,32) row-major
    const float* __restrict__ b_ih, const float* __restrict__ b_hh,
    float* __restrict__ out)
{
    __shared__ float hs[NPB * F];       // 6.4KB
    __shared__ float Ws[96 * 33];       // 12.7KB, stride 33 conflict-free
    __shared__ float bs[96];
    __shared__ unsigned int sgl[CAP2];  // 4KB node-sorted edge list
    __shared__ int cnt[NPB], start[NPB];

    const int t   = threadIdx.x;
    const int bin = blockIdx.x;

    for (int i = t; i < 96 * 32; i += 256) {
        int r = i >> 5, k = i & 31;
        int sr = (r < 32) ? r : r + 32;           // skip f rows 32..63
        Ws[r * 33 + k] = W[sr * 32 + k];
    }
    if (t < 96) { int sr = (t < 32) ? t : t + 32; bs[t] = b_ih[sr] + b_hh[sr]; }
    if (t < NPB) cnt[t] = 0;
    __syncthreads();

    int nE = fill2[bin]; if (nE > CAP2) nE = CAP2;
    const unsigned int* s2 = seg2 + (size_t)bin * CAP2;

    unsigned rV[4]; int rR[4];          // CAP2/256 = 4
    #pragma unroll
    for (int j = 0; j < 4; ++j) {
        int i = t + j * 256;
        if (i < nE) { unsigned v = s2[i]; rV[j] = v; rR[j] = atomicAdd(&cnt[v & 255u], 1); }
    }
    __syncthreads();

    if (t == 0) { int acc = 0; for (int b = 0; b < NPB; ++b) { start[b] = acc; acc += cnt[b]; } }
    __syncthreads();

    #pragma unroll
    for (int j = 0; j < 4; ++j) {
        int i = t + j * 256;
        if (i < nE) { unsigned v = rV[j]; sgl[start[v & 255u] + rR[j]] = v; }
    }
    __syncthreads();

    // gather: group g owns nodes dl = g + 8*m; register accumulate,
    // 16 independent x-row loads in flight per group
    const int lane = t & 31, g = t >> 5;
    for (int dl = g; dl < NPB; dl += 8) {
        int st = start[dl], cn = cnt[dl];
        float acc = 0.0f;
        for (int b = 0; b < cn; b += 16) {
            float xv[16];
            #pragma unroll
            for (int k = 0; k < 16; ++k) {
                int idx = b + k; if (idx > cn - 1) idx = cn - 1;  // clamp (dups masked)
                unsigned v = sgl[st + idx];        // broadcast LDS read
                xv[k] = x[(v >> 8) * F + lane];
            }
            #pragma unroll
            for (int k = 0; k < 16; ++k) acc += (b + k < cn) ? xv[k] : 0.0f;
        }
        hs[dl * F + lane] = acc;                   // plain ds_write, once per node
    }
    __syncthreads();

    // gates: thread -> (node, col j)
    for (int i = t; i < NPB * F; i += 256) {
        int node = i >> 5, j = i & 31;
        const float* h  = &hs[node * F];
        const float* wi = &Ws[j * 33];
        const float* wg = &Ws[(32 + j) * 33];
        const float* wo = &Ws[(64 + j) * 33];
        float ai = bs[j], ag = bs[32 + j], ao = bs[64 + j];
        #pragma unroll
        for (int k = 0; k < F; ++k) {
            float hv = h[k];
            ai += hv * wi[k];
            ag += hv * wg[k];
            ao += hv * wo[k];
        }
        float c  = sigm(ai) * tanh_(ag);
        float hh = sigm(ao) * tanh_(c);
        out[(bin * NPB + node) * F + j] = fmaxf(hh, 0.0f);
    }
}

// ---------------------------------------------------------------------------
extern "C" void kernel_launch(void* const* d_in, const int* in_sizes, int n_in,
                              void* d_out, int out_size, void* d_ws, size_t ws_size,
                              hipStream_t stream) {
    const float* x    = (const float*)d_in[0];
    const int*   src  = (const int*)  d_in[1];
    const int*   dst  = (const int*)  d_in[2];
    const float* W_ih = (const float*)d_in[3];
    // d_in[4] = W_hh : numerically unused
    const float* b_ih = (const float*)d_in[5];
    const float* b_hh = (const float*)d_in[6];
    float* out = (float*)d_out;

    // ws layout: seg1 (8*50*4352*4 = 6.96MB) | seg2 (2000*1024*4 = 8.19MB)
    //          | fill1 (8*64 ints) | fill2 (2000 ints)
    unsigned int* seg1 = (unsigned int*)d_ws;
    unsigned int* seg2 = seg1 + (size_t)NREP * NSB * CAP1R;
    int* fill1 = (int*)(seg2 + (size_t)NBIN * CAP2);
    int* fill2 = fill1 + NREP * 64;

    hipMemsetAsync(fill1, 0, (NREP * 64 + NBIN) * sizeof(int), stream);
    pA<<<NBA,               256, 0, stream>>>(src, dst, seg1, fill1);
    pB<<<NSB * NREP * CHPS, 256, 0, stream>>>(seg1, fill1, seg2, fill2);
    p2<<<NBIN,              256, 0, stream>>>(x, seg2, fill2, W_ih, b_ih, b_hh, out);
}